// Round 20
// baseline (144.403 us; speedup 1.0000x reference)
//
#include <hip/hip_runtime.h>
#include <hip/hip_fp16.h>

typedef _Float16 f16;
typedef _Float16 f16x8 __attribute__((ext_vector_type(8)));
typedef float f32x4 __attribute__((ext_vector_type(4)));

__device__ __forceinline__ f16x8 relu8(f16x8 a) {
#if __has_builtin(__builtin_elementwise_max)
  return __builtin_elementwise_max(a, (f16x8)(f16)0);   // v_pk_max_f16 x4
#else
  f16x8 r;
#pragma unroll
  for (int i = 0; i < 8; i++) r[i] = a[i] > (f16)0 ? a[i] : (f16)0;
  return r;
#endif
}

__device__ __forceinline__ f16x8 bcast8(f16 s) {
  return (f16x8){s, s, s, s, s, s, s, s};
}

__device__ __forceinline__ void atomAddF(float* p, float v) {
#if defined(__AMDGCN__)
  unsafeAtomicAdd(p, v);          // native global_atomic_add_f32
#else
  atomicAdd(p, v);
#endif
}

// ---------------------------------------------------------------------------
// fused (R20): 4 waves/SIMD attempt with LEAN working set.
// 512 blocks x 512 thr (8 waves = 4 il x 2 jh), 2 blocks/CU (LDS 79 KB).
// Wave tile rg=8 x cg=2 -> acc 64 AGPR; launch_bounds(512,4) caps 128
// unified regs/wave. Task = 4 i x 256 j x 32 n (one nq) x 1024 k.
// Balance: blocks 0..255 take one full task (nq=b>>6, jt=1, s=b&63, i<256);
// blocks 256..511 pair (jt0, s=u) with (jt1, s=127-u) — complementary cost
// 16.25 const, same nq -> single 64 KB w2f gather.
// Per kk per wave: 4 ds_read_b128 (hat, w1b, bf[2]) -> 62% LDS pipe.
// C zeroed in-kernel; 4 nq-partials Kq0..3 summed by atta2.
// WRITE_SIZE ~3 MB expected; >>8 MB = register-wall spill canary (R18).
// ---------------------------------------------------------------------------
__global__ __launch_bounds__(512, 4) void k_fused(
    const float* __restrict__ x, const float* __restrict__ W1,
    const float* __restrict__ b1, const float* __restrict__ b2,
    const float* __restrict__ W3, const float* __restrict__ b3,
    const float* __restrict__ W2,
    float* __restrict__ Kq0, float* __restrict__ Kq1,
    float* __restrict__ Kq2, float* __restrict__ Kq3,
    float* __restrict__ C) {
  __shared__ f16 w2f[32768];                 // 64 KB: this nq's B-fragments
  __shared__ f16 w1af[1024], b1f[1024], w1bf[1024];
  __shared__ f16 hat[4096];                  // 8 KB: ha rows for task's 4 i
  __shared__ f16 xs[512];                    // f16(x)

  const int tid = threadIdx.x;
  const int lane = tid & 63, wv = tid >> 6;
  const int il = wv & 3, jh = wv >> 2;       // wave = (i-local, j-half of 128)
  const int cL = lane & 15, q = lane >> 4;
  const int bid = (int)blockIdx.x;

  C[bid * 512 + tid] = 0.f;                  // zero C (replaces memset)

  // --- one-time staging: W1 tables + f16(x)
  if (tid < 128) {
    const int c8 = tid << 3;
    const float4 a0 = *(const float4*)(W1 + c8);
    const float4 a1 = *(const float4*)(W1 + c8 + 4);
    const float4 g0 = *(const float4*)(b1 + c8);
    const float4 g1 = *(const float4*)(b1 + c8 + 4);
    f16x8 oa, og;
    oa[0] = (f16)a0.x; oa[1] = (f16)a0.y; oa[2] = (f16)a0.z; oa[3] = (f16)a0.w;
    oa[4] = (f16)a1.x; oa[5] = (f16)a1.y; oa[6] = (f16)a1.z; oa[7] = (f16)a1.w;
    og[0] = (f16)g0.x; og[1] = (f16)g0.y; og[2] = (f16)g0.z; og[3] = (f16)g0.w;
    og[4] = (f16)g1.x; og[5] = (f16)g1.y; og[6] = (f16)g1.z; og[7] = (f16)g1.w;
    *(f16x8*)(&w1af[c8]) = oa;
    *(f16x8*)(&b1f[c8]) = og;
  } else if (tid < 256) {
    const int c8 = (tid - 128) << 3;
    const float4 a0 = *(const float4*)(W1 + 1024 + c8);
    const float4 a1 = *(const float4*)(W1 + 1024 + c8 + 4);
    f16x8 ob;
    ob[0] = (f16)a0.x; ob[1] = (f16)a0.y; ob[2] = (f16)a0.z; ob[3] = (f16)a0.w;
    ob[4] = (f16)a1.x; ob[5] = (f16)a1.y; ob[6] = (f16)a1.z; ob[7] = (f16)a1.w;
    *(f16x8*)(&w1bf[c8]) = ob;
  } else if (tid < 320) {
    const int c8 = (tid - 256) << 3;
    const float4 x0 = *(const float4*)(x + c8);
    const float4 x1 = *(const float4*)(x + c8 + 4);
    f16x8 ox;
    ox[0] = (f16)x0.x; ox[1] = (f16)x0.y; ox[2] = (f16)x0.z; ox[3] = (f16)x0.w;
    ox[4] = (f16)x1.x; ox[5] = (f16)x1.y; ox[6] = (f16)x1.z; ox[7] = (f16)x1.w;
    *(f16x8*)(&xs[c8]) = ox;
  }

  const int nq = (bid < 256) ? (bid >> 6) : ((bid - 256) >> 6);
  const int ntask = (bid < 256) ? 1 : 2;
  float* __restrict__ Kp = (nq == 0) ? Kq0 : (nq == 1) ? Kq1
                         : (nq == 2) ? Kq2 : Kq3;
  const float badd = (nq == 0) ? b3[0] : 0.f;   // b3 added exactly once

  for (int ti = 0; ti < ntask; ti++) {
    int jt, s;
    if (bid < 256)       { jt = 1; s = bid & 63; }
    else if (ti == 0)    { jt = 0; s = (bid - 256) & 63; }
    else                 { jt = 1; s = 127 - ((bid - 256) & 63); }
    const int i0 = s << 2;
    const int j0w = jt * 256 + jh * 128;       // this wave's 128-j window

    __syncthreads();                 // prior task's LDS reads done; covers staging
    if (ti == 0) {                   // gather this nq's W2 fragments (64 KB)
      #pragma unroll
      for (int p = 0; p < 8; p++) {
        const int sl = p * 512 + tid;          // slot 0..4095
        const int frag = sl >> 6, l = sl & 63;
        const int cgL = frag >> 5, kb2 = frag & 31;
        const int q2 = l >> 4, cL2 = l & 15;
        const float* src = W2 + (kb2 * 32 + q2 * 8) * 128 + nq * 32 + cgL * 16 + cL2;
        f16x8 o;
        #pragma unroll
        for (int e = 0; e < 8; e++) o[e] = (f16)src[e * 128];
        *(f16x8*)(&w2f[frag * 512 + l * 8]) = o;
      }
    }
    {  // hat[il][k] = f16(x[i0+il]*W1a[k] + b1[k]); 512 thr x 8 f16
      const int il_s = tid >> 7, kb = (tid & 127) << 3;
      const f16x8 xv = bcast8(xs[i0 + il_s]);
      const f16x8 wa = *(const f16x8*)(&w1af[kb]);
      const f16x8 bb = *(const f16x8*)(&b1f[kb]);
      *(f16x8*)(&hat[il_s * 1024 + kb]) = xv * wa + bb;
    }
    __syncthreads();

    const int i = i0 + il;
    const int dij = i - j0w;
    const int rgmin = (dij > 0) ? (dij >> 4) : 0;   // wave-uniform skip

    f16 xjs[8];
    #pragma unroll
    for (int rg = 0; rg < 8; rg++) xjs[rg] = xs[j0w + rg * 16 + cL];

    f32x4 acc[8][2];
    #pragma unroll
    for (int rg = 0; rg < 8; rg++)
      #pragma unroll
      for (int cg = 0; cg < 2; cg++) acc[rg][cg] = (f32x4){0.f, 0.f, 0.f, 0.f};

    const f16* hrow  = hat + il * 1024 + q * 8;
    const f16* wrow  = w1bf + q * 8;
    const f16* bbase = w2f + lane * 8;

    for (int kk = 0; kk < 32; ++kk) {
      const f16x8 hv = *(const f16x8*)(hrow + kk * 32);
      const f16x8 wb = *(const f16x8*)(wrow + kk * 32);
      f16x8 bf[2];
      #pragma unroll
      for (int cg = 0; cg < 2; cg++)
        bf[cg] = *(const f16x8*)(bbase + (cg * 32 + kk) * 512);
      #pragma unroll
      for (int rg = 0; rg < 8; rg++) {
        if (rg >= rgmin) {
          const f16x8 af = relu8(bcast8(xjs[rg]) * wb + hv);
          #pragma unroll
          for (int cg = 0; cg < 2; cg++)
            acc[rg][cg] = __builtin_amdgcn_mfma_f32_16x16x32_f16(af, bf[cg], acc[rg][cg], 0, 0, 0);
        }
      }
    }

    // --- epilogue: dot over this nq's 32 n; direct global writes
    float b2v[2], w3v[2];
    #pragma unroll
    for (int cg = 0; cg < 2; cg++) {
      const int n = nq * 32 + cg * 16 + cL;
      b2v[cg] = b2[n];
      w3v[cg] = W3[n];
    }
    #pragma unroll
    for (int rg = 0; rg < 8; rg++) {
      if (rg >= rgmin) {
        #pragma unroll
        for (int r = 0; r < 4; r++) {
          float ssum = 0.f;
          #pragma unroll
          for (int cg = 0; cg < 2; cg++)
            ssum = fmaf(fmaxf(acc[rg][cg][r] + b2v[cg], 0.f), w3v[cg], ssum);
          ssum += __shfl_xor(ssum, 1, 64);
          ssum += __shfl_xor(ssum, 2, 64);
          ssum += __shfl_xor(ssum, 4, 64);
          ssum += __shfl_xor(ssum, 8, 64);
          if (cL == 0) {
            const int j = j0w + rg * 16 + q * 4 + r;  // C row = q*4 + reg
            if (j >= i) Kp[i * 512 + j] = ssum + badd;
          }
        }
      }
    }
  }
}

// ---------------------------------------------------------------------------
// atta2 (R18's 4-array version): split-K parallel KtK. One block per
// (pair a<=b, i-chunk of 32) = 816 blocks. float4 loads of the 4 partials;
// 32x32 tile accumulated into pre-zeroed C via native f32 atomics.
// ---------------------------------------------------------------------------
__global__ __launch_bounds__(256) void k_atta2(const float* __restrict__ K0,
                                               const float* __restrict__ K1,
                                               const float* __restrict__ K2,
                                               const float* __restrict__ K3,
                                               float* __restrict__ C) {
  __shared__ float sp[32 * 36], sq[32 * 36];
  int a = 0, rem = (int)blockIdx.x;
  #pragma unroll
  for (int aa = 0; aa < 16; aa++) {
    const int c = (16 - aa) * (aa + 1);
    if (rem < c) { a = aa; break; }
    rem -= c;
  }
  const int b = a + rem / (a + 1);
  const int ic = rem % (a + 1);
  const int pb = a * 32, qb = b * 32, i0 = ic * 32;

  const int tid = threadIdx.x;
  const int ii = tid >> 3, p4 = (tid & 7) << 2;
  const int irow = i0 + ii;
  {
    const int gp = irow * 512 + pb + p4, gq = irow * 512 + qb + p4;
    const float4 a0 = *(const float4*)(K0 + gp);
    const float4 a1 = *(const float4*)(K1 + gp);
    const float4 a2 = *(const float4*)(K2 + gp);
    const float4 a3 = *(const float4*)(K3 + gp);
    const float4 b0 = *(const float4*)(K0 + gq);
    const float4 b1 = *(const float4*)(K1 + gq);
    const float4 b2 = *(const float4*)(K2 + gq);
    const float4 b3 = *(const float4*)(K3 + gq);
    float vp[4] = {a0.x + a1.x + a2.x + a3.x, a0.y + a1.y + a2.y + a3.y,
                   a0.z + a1.z + a2.z + a3.z, a0.w + a1.w + a2.w + a3.w};
    float vq[4] = {b0.x + b1.x + b2.x + b3.x, b0.y + b1.y + b2.y + b3.y,
                   b0.z + b1.z + b2.z + b3.z, b0.w + b1.w + b2.w + b3.w};
    #pragma unroll
    for (int e = 0; e < 4; e++) {
      sp[ii * 36 + p4 + e] = (irow <= pb + p4 + e) ? vp[e] : 0.f;  // triu mask
      sq[ii * 36 + p4 + e] = (irow <= qb + p4 + e) ? vq[e] : 0.f;
    }
  }
  __syncthreads();

  const int tx = tid & 15, ty = tid >> 4;
  float c00 = 0.f, c01 = 0.f, c10 = 0.f, c11 = 0.f;
  #pragma unroll 8
  for (int k = 0; k < 32; k++) {
    const float a0 = sp[k * 36 + ty * 2], a1 = sp[k * 36 + ty * 2 + 1];
    const float b0 = sq[k * 36 + tx * 2], b1 = sq[k * 36 + tx * 2 + 1];
    c00 = fmaf(a0, b0, c00); c01 = fmaf(a0, b1, c01);
    c10 = fmaf(a1, b0, c10); c11 = fmaf(a1, b1, c11);
  }
  const int p0 = pb + ty * 2, q0 = qb + tx * 2;
  atomAddF(&C[p0 * 512 + q0], c00);       atomAddF(&C[p0 * 512 + q0 + 1], c01);
  atomAddF(&C[(p0 + 1) * 512 + q0], c10); atomAddF(&C[(p0 + 1) * 512 + q0 + 1], c11);
  if (pb != qb) {
    atomAddF(&C[q0 * 512 + p0], c00);       atomAddF(&C[(q0 + 1) * 512 + p0], c01);
    atomAddF(&C[q0 * 512 + p0 + 1], c10);   atomAddF(&C[(q0 + 1) * 512 + p0 + 1], c11);
  }
}

extern "C" void kernel_launch(void* const* d_in, const int* in_sizes, int n_in,
                              void* d_out, int out_size, void* d_ws, size_t ws_size,
                              hipStream_t stream) {
  const float* x  = (const float*)d_in[0];
  const float* W1 = (const float*)d_in[1];
  const float* b1 = (const float*)d_in[2];
  const float* W2 = (const float*)d_in[3];
  const float* b2 = (const float*)d_in[4];
  const float* W3 = (const float*)d_in[5];
  const float* b3 = (const float*)d_in[6];
  float* out = (float*)d_out;
  char* ws = (char*)d_ws;

  float* Kq0 = (float*)ws;                          // 4x 1 MB nq-partial K
  float* Kq1 = (float*)(ws + (1 << 20));
  float* Kq2 = (float*)(ws + (2 << 20));
  float* Kq3 = (float*)(ws + (3 << 20));

  k_fused<<<512, 512, 0, stream>>>(x, W1, b1, b2, W3, b3, W2,
                                   Kq0, Kq1, Kq2, Kq3, out);
  k_atta2<<<816, 256, 0, stream>>>(Kq0, Kq1, Kq2, Kq3, out);
}

// Round 21
// 121.359 us; speedup vs baseline: 1.1899x; 1.1899x over previous
//
#include <hip/hip_runtime.h>
#include <hip/hip_fp16.h>

typedef _Float16 f16;
typedef _Float16 f16x8 __attribute__((ext_vector_type(8)));
typedef float f32x4 __attribute__((ext_vector_type(4)));

__device__ __forceinline__ f16x8 relu8(f16x8 a) {
#if __has_builtin(__builtin_elementwise_max)
  return __builtin_elementwise_max(a, (f16x8)(f16)0);   // v_pk_max_f16 x4
#else
  f16x8 r;
#pragma unroll
  for (int i = 0; i < 8; i++) r[i] = a[i] > (f16)0 ? a[i] : (f16)0;
  return r;
#endif
}

__device__ __forceinline__ f16x8 bcast8(f16 s) {
  return (f16x8){s, s, s, s, s, s, s, s};
}

__device__ __forceinline__ void atomAddF(float* p, float v) {
#if defined(__AMDGCN__)
  unsafeAtomicAdd(p, v);          // native global_atomic_add_f32
#else
  atomicAdd(p, v);
#endif
}

// ---------------------------------------------------------------------------
// fused (R19 final): 256 persistent blocks, 512 thr = 8 waves, 1 block/CU.
// Structural optimum after 20 rounds:
// - 16x16x32 MFMA, wave tile rg=8 x cg=4 (acc 128 AGPR). 32x32 regressed
//   (R15: more LDS reads/K, longer phase-lock chains).
// - 2 waves/SIMD is the register-file optimum: acc 128 AGPR + ~110 VGPR
//   working set = 240/256. All >2-wave or prefetch attempts spilled
//   (R10/R12/R18/R20 — WRITE_SIZE canary 9-34 MB each time).
// - W2 nh-slice (128 KB) LDS-resident, gathered directly from global on nh
//   change; A-fragments regenerated in registers (relu(xj*w1b + xi*w1a+b1)).
// - R14 balanced task map: 128 cheap diagonal tasks paired complementary in
//   {0..63,256..319}; 192 full tasks in {64..255}; max load 1.06 full-equiv.
// - C zeroed in-kernel; no k_prep; 2 dispatches total (~3 us/dispatch).
// - No in-kernel grid barrier (R16: +100 us).
// WRITE_SIZE ~2.1 MB = no-spill canary.
// ---------------------------------------------------------------------------
__global__ __launch_bounds__(512, 2) void k_fused(
    const float* __restrict__ x, const float* __restrict__ W1,
    const float* __restrict__ b1, const float* __restrict__ b2,
    const float* __restrict__ W3, const float* __restrict__ b3,
    const float* __restrict__ W2,
    float* __restrict__ Kp0, float* __restrict__ Kp1,
    float* __restrict__ C) {
  __shared__ f16 w2f[65536];                 // 128 KB: current nh's B-fragments
  __shared__ f16 w1af[1024], b1f[1024], w1bf[1024];
  __shared__ f16 hat[8192];                  // 16 KB: ha rows for task's 8 i
  __shared__ f16 xs[512];                    // f16(x)

  const int tid = threadIdx.x;
  const int lane = tid & 63, wv = tid >> 6;
  const int cL = lane & 15, q = lane >> 4;

  {  // zero this block's 4 KB chunk of C (replaces the memset dispatch)
    float2 z = {0.f, 0.f};
    ((float2*)C)[blockIdx.x * 512 + tid] = z;
  }

  // --- one-time staging: W1 tables + f16(x)
  if (tid < 128) {
    const int c8 = tid << 3;
    const float4 a0 = *(const float4*)(W1 + c8);
    const float4 a1 = *(const float4*)(W1 + c8 + 4);
    const float4 g0 = *(const float4*)(b1 + c8);
    const float4 g1 = *(const float4*)(b1 + c8 + 4);
    f16x8 oa, og;
    oa[0] = (f16)a0.x; oa[1] = (f16)a0.y; oa[2] = (f16)a0.z; oa[3] = (f16)a0.w;
    oa[4] = (f16)a1.x; oa[5] = (f16)a1.y; oa[6] = (f16)a1.z; oa[7] = (f16)a1.w;
    og[0] = (f16)g0.x; og[1] = (f16)g0.y; og[2] = (f16)g0.z; og[3] = (f16)g0.w;
    og[4] = (f16)g1.x; og[5] = (f16)g1.y; og[6] = (f16)g1.z; og[7] = (f16)g1.w;
    *(f16x8*)(&w1af[c8]) = oa;
    *(f16x8*)(&b1f[c8]) = og;
  } else if (tid < 256) {
    const int c8 = (tid - 128) << 3;
    const float4 a0 = *(const float4*)(W1 + 1024 + c8);
    const float4 a1 = *(const float4*)(W1 + 1024 + c8 + 4);
    f16x8 ob;
    ob[0] = (f16)a0.x; ob[1] = (f16)a0.y; ob[2] = (f16)a0.z; ob[3] = (f16)a0.w;
    ob[4] = (f16)a1.x; ob[5] = (f16)a1.y; ob[6] = (f16)a1.z; ob[7] = (f16)a1.w;
    *(f16x8*)(&w1bf[c8]) = ob;
  } else if (tid < 320) {
    const int c8 = (tid - 256) << 3;
    const float4 x0 = *(const float4*)(x + c8);
    const float4 x1 = *(const float4*)(x + c8 + 4);
    f16x8 ox;
    ox[0] = (f16)x0.x; ox[1] = (f16)x0.y; ox[2] = (f16)x0.z; ox[3] = (f16)x0.w;
    ox[4] = (f16)x1.x; ox[5] = (f16)x1.y; ox[6] = (f16)x1.z; ox[7] = (f16)x1.w;
    *(f16x8*)(&xs[c8]) = ox;
  }

  int cur_nh = -1;

  for (int t = (int)blockIdx.x; t < 320; t += 256) {
    // --- task map (R14): cheap diagonal in {0..63, 256..319}, full in {64..255}
    int nh, jt, s;
    if (t < 64 || t >= 256) {
      const int b = (t < 64) ? t : (t - 256);
      nh = b & 1;
      const int jd = b >> 1;              // 0..31
      const int jt1 = jd >> 4, l = jd & 15;
      if (t < 64) { jt = jt1;            s = jt * 16 + l; }
      else        { jt = (jt1 + 2) & 3;  s = jt * 16 + (15 - l); }
    } else {
      const int f = t - 64;               // 0..191
      nh = f & 1;
      const int jf = f >> 1;              // 0..95
      if (jf < 16)      { jt = 1; s = jf; }
      else if (jf < 48) { jt = 2; s = jf - 16; }
      else              { jt = 3; s = jf - 48; }
    }
    const int i0 = s << 3, j0 = jt << 7;
    float* __restrict__ Kp = nh ? Kp1 : Kp0;

    __syncthreads();                  // prior task's LDS reads done; covers one-time staging
    if (nh != cur_nh) {               // gather this nh's W2 fragments from GLOBAL
      #pragma unroll
      for (int p = 0; p < 16; p++) {
        const int sl = p * 512 + tid;           // slot 0..8191
        const int frag = sl >> 6, l = sl & 63;
        const int cgL = frag >> 5, kb2 = frag & 31;
        const int q2 = l >> 4, cL2 = l & 15;
        const int n = nh * 64 + cgL * 16 + cL2;
        const float* src = W2 + (kb2 * 32 + q2 * 8) * 128 + n;
        f16x8 o;
        #pragma unroll
        for (int e = 0; e < 8; e++) o[e] = (f16)src[e * 128];
        *(f16x8*)(&w2f[frag * 512 + l * 8]) = o;
      }
      cur_nh = nh;
    }
    {  // hat[il][k] = f16(x[i0+il]*W1a[k] + b1[k]); 512 thr x 16 f16
      const int il_s = tid >> 6, kb = (tid & 63) << 4;
      const f16x8 xv = bcast8(xs[i0 + il_s]);
      const f16x8 wa0 = *(const f16x8*)(&w1af[kb]);
      const f16x8 wa1 = *(const f16x8*)(&w1af[kb + 8]);
      const f16x8 bb0 = *(const f16x8*)(&b1f[kb]);
      const f16x8 bb1 = *(const f16x8*)(&b1f[kb + 8]);
      *(f16x8*)(&hat[il_s * 1024 + kb])     = xv * wa0 + bb0;
      *(f16x8*)(&hat[il_s * 1024 + kb + 8]) = xv * wa1 + bb1;
    }
    __syncthreads();

    const int i = i0 + wv;
    const int dij = i - j0;
    const int rgmin = (dij > 0) ? (dij >> 4) : 0;   // wave-uniform skip

    f16 xjs[8];
    #pragma unroll
    for (int rg = 0; rg < 8; rg++) xjs[rg] = xs[j0 + rg * 16 + cL];

    f32x4 acc[8][4];
    #pragma unroll
    for (int rg = 0; rg < 8; rg++)
      #pragma unroll
      for (int cg = 0; cg < 4; cg++) acc[rg][cg] = (f32x4){0.f, 0.f, 0.f, 0.f};

    const f16* hrow  = hat + wv * 1024 + q * 8;
    const f16* wrow  = w1bf + q * 8;
    const f16* bbase = w2f + lane * 8;

    for (int kk = 0; kk < 32; ++kk) {
      const f16x8 hv = *(const f16x8*)(hrow + kk * 32);
      const f16x8 wb = *(const f16x8*)(wrow + kk * 32);
      f16x8 bf[4];
      #pragma unroll
      for (int cg = 0; cg < 4; cg++)
        bf[cg] = *(const f16x8*)(bbase + (cg * 32 + kk) * 512);
      #pragma unroll
      for (int rg = 0; rg < 8; rg++) {
        if (rg >= rgmin) {
          const f16x8 af = relu8(bcast8(xjs[rg]) * wb + hv);
          #pragma unroll
          for (int cg = 0; cg < 4; cg++)
            acc[rg][cg] = __builtin_amdgcn_mfma_f32_16x16x32_f16(af, bf[cg], acc[rg][cg], 0, 0, 0);
        }
      }
    }

    // --- epilogue: dot over this nh's 64 n; direct global writes (1 i/wave)
    float b2v[4], w3v[4];
    #pragma unroll
    for (int cg = 0; cg < 4; cg++) {
      b2v[cg] = b2[nh * 64 + cg * 16 + cL];
      w3v[cg] = W3[nh * 64 + cg * 16 + cL];
    }
    const float badd = (nh == 0) ? b3[0] : 0.f;   // b3 added exactly once
    #pragma unroll
    for (int rg = 0; rg < 8; rg++) {
      if (rg >= rgmin) {
        #pragma unroll
        for (int r = 0; r < 4; r++) {
          float ssum = 0.f;
          #pragma unroll
          for (int cg = 0; cg < 4; cg++)
            ssum = fmaf(fmaxf(acc[rg][cg][r] + b2v[cg], 0.f), w3v[cg], ssum);
          ssum += __shfl_xor(ssum, 1, 64);
          ssum += __shfl_xor(ssum, 2, 64);
          ssum += __shfl_xor(ssum, 4, 64);
          ssum += __shfl_xor(ssum, 8, 64);
          if (cL == 0) {
            const int j = j0 + rg * 16 + q * 4 + r;  // C row = q*4 + reg
            if (j >= i) Kp[i * 512 + j] = ssum + badd;
          }
        }
      }
    }
  }
}

// ---------------------------------------------------------------------------
// atta2 (R17, proven): split-K parallel KtK. One block per (pair a<=b,
// i-chunk of 32) = 816 blocks. float4 loads of Kp0+Kp1; 32x32 partial tile
// accumulated into pre-zeroed C via native f32 atomics; mirror guarded.
// ---------------------------------------------------------------------------
__global__ __launch_bounds__(256) void k_atta2(const float* __restrict__ K0,
                                               const float* __restrict__ K1,
                                               float* __restrict__ C) {
  __shared__ float sp[32 * 36], sq[32 * 36];
  int a = 0, rem = (int)blockIdx.x;
  #pragma unroll
  for (int aa = 0; aa < 16; aa++) {
    const int c = (16 - aa) * (aa + 1);
    if (rem < c) { a = aa; break; }
    rem -= c;
  }
  const int b = a + rem / (a + 1);
  const int ic = rem % (a + 1);
  const int pb = a * 32, qb = b * 32, i0 = ic * 32;

  const int tid = threadIdx.x;
  const int ii = tid >> 3, p4 = (tid & 7) << 2;
  const int irow = i0 + ii;
  {
    const int gp = irow * 512 + pb + p4, gq = irow * 512 + qb + p4;
    const float4 a0 = *(const float4*)(K0 + gp);
    const float4 a1 = *(const float4*)(K1 + gp);
    const float4 b0 = *(const float4*)(K0 + gq);
    const float4 b1 = *(const float4*)(K1 + gq);
    float vp[4] = {a0.x + a1.x, a0.y + a1.y, a0.z + a1.z, a0.w + a1.w};
    float vq[4] = {b0.x + b1.x, b0.y + b1.y, b0.z + b1.z, b0.w + b1.w};
    #pragma unroll
    for (int e = 0; e < 4; e++) {
      sp[ii * 36 + p4 + e] = (irow <= pb + p4 + e) ? vp[e] : 0.f;  // triu mask
      sq[ii * 36 + p4 + e] = (irow <= qb + p4 + e) ? vq[e] : 0.f;
    }
  }
  __syncthreads();

  const int tx = tid & 15, ty = tid >> 4;
  float c00 = 0.f, c01 = 0.f, c10 = 0.f, c11 = 0.f;
  #pragma unroll 8
  for (int k = 0; k < 32; k++) {
    const float a0 = sp[k * 36 + ty * 2], a1 = sp[k * 36 + ty * 2 + 1];
    const float b0 = sq[k * 36 + tx * 2], b1 = sq[k * 36 + tx * 2 + 1];
    c00 = fmaf(a0, b0, c00); c01 = fmaf(a0, b1, c01);
    c10 = fmaf(a1, b0, c10); c11 = fmaf(a1, b1, c11);
  }
  const int p0 = pb + ty * 2, q0 = qb + tx * 2;
  atomAddF(&C[p0 * 512 + q0], c00);       atomAddF(&C[p0 * 512 + q0 + 1], c01);
  atomAddF(&C[(p0 + 1) * 512 + q0], c10); atomAddF(&C[(p0 + 1) * 512 + q0 + 1], c11);
  if (pb != qb) {
    atomAddF(&C[q0 * 512 + p0], c00);       atomAddF(&C[(q0 + 1) * 512 + p0], c01);
    atomAddF(&C[q0 * 512 + p0 + 1], c10);   atomAddF(&C[(q0 + 1) * 512 + p0 + 1], c11);
  }
}

extern "C" void kernel_launch(void* const* d_in, const int* in_sizes, int n_in,
                              void* d_out, int out_size, void* d_ws, size_t ws_size,
                              hipStream_t stream) {
  const float* x  = (const float*)d_in[0];
  const float* W1 = (const float*)d_in[1];
  const float* b1 = (const float*)d_in[2];
  const float* W2 = (const float*)d_in[3];
  const float* b2 = (const float*)d_in[4];
  const float* W3 = (const float*)d_in[5];
  const float* b3 = (const float*)d_in[6];
  float* out = (float*)d_out;
  char* ws = (char*)d_ws;

  float* Kp0 = (float*)ws;                          // 1 MB partial K (n 0..63)
  float* Kp1 = (float*)(ws + (1 << 20));            // 1 MB partial K (n 64..127)

  k_fused<<<256, 512, 0, stream>>>(x, W1, b1, b2, W3, b3, W2, Kp0, Kp1, out);
  k_atta2<<<816, 256, 0, stream>>>(Kp0, Kp1, out);
}